// Round 1
// baseline (547.505 us; speedup 1.0000x reference)
//
#include <hip/hip_runtime.h>

#define BB 2
#define FF 2
#define CC 3
#define HH 256
#define WW 512
#define DD 32
#define HW (HH*WW)
#define CV_SIZE (BB*DD*HW)

__device__ __forceinline__ int refl(int i, int n) { return i < 0 ? -i : (i >= n ? 2*n-2-i : i); }

// 4x4 Gauss-Jordan inverse with partial pivoting (f32, matches jnp.linalg.inv to ulps)
__device__ void inv4(const float* m, float* out) {
  float a[4][8];
  for (int i = 0; i < 4; ++i)
    for (int j = 0; j < 4; ++j) { a[i][j] = m[i*4+j]; a[i][j+4] = (i==j) ? 1.f : 0.f; }
  for (int col = 0; col < 4; ++col) {
    int piv = col; float best = fabsf(a[col][col]);
    for (int r = col+1; r < 4; ++r) { float v = fabsf(a[r][col]); if (v > best) { best = v; piv = r; } }
    if (piv != col) for (int j = 0; j < 8; ++j) { float t = a[col][j]; a[col][j] = a[piv][j]; a[piv][j] = t; }
    float invd = 1.0f / a[col][col];
    for (int j = 0; j < 8; ++j) a[col][j] *= invd;
    for (int r = 0; r < 4; ++r) {
      if (r == col) continue;
      float f = a[r][col];
      for (int j = 0; j < 8; ++j) a[r][j] -= f * a[col][j];
    }
  }
  for (int i = 0; i < 4; ++i) for (int j = 0; j < 4; ++j) out[i*4+j] = a[i][j+4];
}

__global__ void setup_kernel(const float* __restrict__ kK, const float* __restrict__ Ks,
                             const float* __restrict__ kpose, const float* __restrict__ poses,
                             float* __restrict__ P, float* __restrict__ IK) {
  int t = threadIdx.x;
  if (t < BB) {
    float inv[16]; inv4(kK + t*16, inv);
    float* o = IK + t*9;
    o[0]=inv[0]; o[1]=inv[1]; o[2]=inv[2];
    o[3]=inv[4]; o[4]=inv[5]; o[5]=inv[6];
    o[6]=inv[8]; o[7]=inv[9]; o[8]=inv[10];
  }
  if (t >= 32 && t < 32 + FF*BB) {
    int i = t - 32;               // i = f*BB + b
    int b = i % BB;
    float ip[16]; inv4(poses + i*16, ip);
    float T[16];
    for (int r = 0; r < 4; ++r)
      for (int c = 0; c < 4; ++c) {
        float s = 0.f;
        for (int k = 0; k < 4; ++k) s += ip[r*4+k] * kpose[b*16 + k*4 + c];
        T[r*4+c] = s;
      }
    for (int r = 0; r < 3; ++r)
      for (int c = 0; c < 4; ++c) {
        float s = 0.f;
        for (int k = 0; k < 4; ++k) s += Ks[i*16 + r*4 + k] * T[k*4 + c];
        P[i*12 + r*4 + c] = s;
      }
  }
}

struct Proj { float x, y; };

__device__ __forceinline__ Proj project(const float* __restrict__ Pm,
                                        float camx, float camy, float camz, int d) {
  const float invd0 = 1.0f/3.0f;
  const float step  = (0.0125f - (1.0f/3.0f)) / 31.0f;   // (1/80 - 1/3)/(D-1), f32 like jnp.linspace
  float depth = 1.0f / (invd0 + step * (float)d);
  float X = depth*camx, Y = depth*camy, Z = depth*camz;
  float cp0 = Pm[0]*X + Pm[1]*Y + Pm[2]*Z  + Pm[3];
  float cp1 = Pm[4]*X + Pm[5]*Y + Pm[6]*Z  + Pm[7];
  float cp2 = Pm[8]*X + Pm[9]*Y + Pm[10]*Z + Pm[11];
  float den = cp2 + 1e-7f;
  float px = cp0 / den;
  float py = cp1 / den;
  float gx = px / (float)(WW-1);
  float gy = py / (float)(HH-1);
  gx = fminf(fmaxf((gx - 0.5f)*2.0f, -2.0f), 2.0f);
  gy = fminf(fmaxf((gy - 0.5f)*2.0f, -2.0f), 2.0f);
  Proj pr;
  pr.x = (gx + 1.0f) * ((float)WW*0.5f) - 0.5f;
  pr.y = (gy + 1.0f) * ((float)HH*0.5f) - 0.5f;
  return pr;
}

// warp one (b,f): writes wimg[d][c][h][w] = bilinear_sample + 0.5
__global__ void warp_kernel(const float* __restrict__ frame, const float* __restrict__ Pm,
                            const float* __restrict__ IK, float* __restrict__ wimg) {
  int idx = blockIdx.x * blockDim.x + threadIdx.x;
  if (idx >= DD*HW) return;
  int w = idx % WW;
  int h = (idx / WW) % HH;
  int d = idx / HW;
  float fw = (float)w, fh = (float)h;
  float camx = IK[0]*fw + IK[1]*fh + IK[2];
  float camy = IK[3]*fw + IK[4]*fh + IK[5];
  float camz = IK[6]*fw + IK[7]*fh + IK[8];
  Proj pr = project(Pm, camx, camy, camz, d);
  float x = pr.x, y = pr.y;
  float x0f = floorf(x), y0f = floorf(y);
  float x1f = x0f + 1.f, y1f = y0f + 1.f;
  float wa = (x1f-x)*(y1f-y);
  float wb = (x1f-x)*(y-y0f);
  float wc = (x-x0f)*(y1f-y);
  float wd = (x-x0f)*(y-y0f);
  bool vx0 = (x0f >= 0.f) && (x0f <= (float)(WW-1));
  bool vx1 = (x1f >= 0.f) && (x1f <= (float)(WW-1));
  bool vy0 = (y0f >= 0.f) && (y0f <= (float)(HH-1));
  bool vy1 = (y1f >= 0.f) && (y1f <= (float)(HH-1));
  int x0 = (int)fminf(fmaxf(x0f, 0.f), (float)(WW-1));
  int x1 = (int)fminf(fmaxf(x1f, 0.f), (float)(WW-1));
  int y0 = (int)fminf(fmaxf(y0f, 0.f), (float)(HH-1));
  int y1 = (int)fminf(fmaxf(y1f, 0.f), (float)(HH-1));
  #pragma unroll
  for (int c = 0; c < CC; ++c) {
    const float* im = frame + c*HW;
    float va = (vx0 && vy0) ? im[y0*WW + x0] : 0.f;
    float vb = (vx0 && vy1) ? im[y1*WW + x0] : 0.f;
    float vc = (vx1 && vy0) ? im[y0*WW + x1] : 0.f;
    float vd = (vx1 && vy1) ? im[y1*WW + x1] : 0.f;
    float v = va*wa + vb*wb + vc*wc + vd*wd;
    wimg[(d*CC + c)*HW + h*WW + w] = v + 0.5f;
  }
}

__device__ __forceinline__ float borderVal(float xif, float yif) {
  if (!((xif >= 0.f) && (xif <= (float)(WW-1)) && (yif >= 0.f) && (yif <= (float)(HH-1)))) return 0.f;
  int xi = (int)xif, yi = (int)yif;
  return (xi >= 2 && xi < WW-2 && yi >= 2 && yi < HH-2) ? 1.f : 0.f;
}

// per (b,f): wmask = border(h,w) * AND_d(bilinear(border_mask) != 0)
__global__ void mask_kernel(const float* __restrict__ Pm, const float* __restrict__ IK,
                            float* __restrict__ wmask) {
  int p = blockIdx.x * blockDim.x + threadIdx.x;
  if (p >= HW) return;
  int w = p % WW, h = p / WW;
  float fw = (float)w, fh = (float)h;
  float camx = IK[0]*fw + IK[1]*fh + IK[2];
  float camy = IK[3]*fw + IK[4]*fh + IK[5];
  float camz = IK[6]*fw + IK[7]*fh + IK[8];
  bool ok = true;
  for (int d = 0; d < DD; ++d) {
    Proj pr = project(Pm, camx, camy, camz, d);
    float x = pr.x, y = pr.y;
    float x0f = floorf(x), y0f = floorf(y);
    float x1f = x0f+1.f, y1f = y0f+1.f;
    float wa = (x1f-x)*(y1f-y);
    float wb = (x1f-x)*(y-y0f);
    float wc = (x-x0f)*(y1f-y);
    float wd = (x-x0f)*(y-y0f);
    float m = borderVal(x0f,y0f)*wa + borderVal(x0f,y1f)*wb +
              borderVal(x1f,y0f)*wc + borderVal(x1f,y1f)*wd;
    ok = ok && (m != 0.f);
  }
  bool inb = (w >= 2 && w < WW-2 && h >= 2 && h < HH-2);
  wmask[p] = (inb && ok) ? 1.f : 0.f;
}

// keyframe SSIM stats: mu_y, sigma_y per (b,c,h,w) — f/d independent, computed once
__global__ void kfstats_kernel(const float* __restrict__ kf, float* __restrict__ muy,
                               float* __restrict__ sigy) {
  int idx = blockIdx.x*blockDim.x + threadIdx.x;
  if (idx >= BB*CC*HW) return;
  int w = idx % WW, h = (idx/WW) % HH;
  int bc = idx / HW;
  const float* ys = kf + bc*HW;
  float s = 0.f, s2 = 0.f;
  #pragma unroll
  for (int dy = -1; dy <= 1; ++dy) {
    int rh = refl(h+dy, HH);
    #pragma unroll
    for (int dx = -1; dx <= 1; ++dx) {
      int rw = refl(w+dx, WW);
      float yv = ys[rh*WW+rw] + 0.5f;
      s += yv; s2 += yv*yv;
    }
  }
  float mu = s / 9.0f;
  muy[idx] = mu;
  sigy[idx] = s2/9.0f - mu*mu;
}

// per (b,f): SSIM diff, channel-weighted sum -> diffw[d][h][w]
__global__ void ssim_kernel(const float* __restrict__ wimg, const float* __restrict__ kf_b,
                            const float* __restrict__ muy_b, const float* __restrict__ sigy_b,
                            float* __restrict__ diffw) {
  int idx = blockIdx.x*blockDim.x + threadIdx.x;
  if (idx >= DD*HW) return;
  int w = idx % WW, h = (idx/WW)%HH, d = idx/HW;
  const float cw[3] = {5.f/32.f, 16.f/32.f, 11.f/32.f};
  float acc = 0.f;
  #pragma unroll
  for (int c = 0; c < CC; ++c) {
    const float* xs = wimg + (d*CC+c)*HW;
    const float* ys = kf_b + c*HW;
    float sx=0.f, sxx=0.f, sxy=0.f;
    #pragma unroll
    for (int dy=-1; dy<=1; ++dy) {
      int rh = refl(h+dy, HH);
      #pragma unroll
      for (int dx=-1; dx<=1; ++dx) {
        int rw = refl(w+dx, WW);
        float xv = xs[rh*WW+rw];
        float yv = ys[rh*WW+rw] + 0.5f;
        sx += xv; sxx += xv*xv; sxy += xv*yv;
      }
    }
    float mux = sx / 9.0f;
    float sigx = sxx/9.0f - mux*mux;
    int pp = c*HW + h*WW + w;
    float mu_y = muy_b[pp];
    float sig_y = sigy_b[pp];
    float sigxy = sxy/9.0f - mux*mu_y;
    float n  = (2.f*mux*mu_y + 1e-4f) * (2.f*sigxy + 9e-4f);
    float dn = (mux*mux + mu_y*mu_y + 1e-4f) * (sigx + sig_y + 9e-4f);
    float v = (1.f - n/dn) * 0.5f;
    v = fminf(fmaxf(v, 0.f), 1.f);
    acc += cw[c]*v;
  }
  diffw[idx] = acc;
}

// per (b,f): 3x3 zero-padded box sum / 9 -> raw sad stored into sfcv region of d_out
__global__ void sad_kernel(const float* __restrict__ diffw, float* __restrict__ sadout) {
  int idx = blockIdx.x*blockDim.x + threadIdx.x;
  if (idx >= DD*HW) return;
  int w = idx % WW, h = (idx/WW)%HH, d = idx/HW;
  float s = 0.f;
  #pragma unroll
  for (int dy=-1; dy<=1; ++dy) {
    int hh = h+dy; if (hh < 0 || hh >= HH) continue;
    #pragma unroll
    for (int dx=-1; dx<=1; ++dx) {
      int ww2 = w+dx; if (ww2 < 0 || ww2 >= WW) continue;
      s += diffw[(d*HH+hh)*WW + ww2];
    }
  }
  sadout[idx] = s / 9.0f;
}

// per (b,f): weight = (1 - (sum_d exp(-10*(sad-min)^2) - 1)/31) * wmask
__global__ void weight_kernel(const float* __restrict__ sad_fb, const float* __restrict__ wmask_fb,
                              float* __restrict__ weight_fb) {
  int p = blockIdx.x*blockDim.x + threadIdx.x;
  if (p >= HW) return;
  float mn = 3.0e38f;
  for (int d = 0; d < DD; ++d) mn = fminf(mn, sad_fb[d*HW + p]);
  float s = 0.f;
  for (int d = 0; d < DD; ++d) { float t = sad_fb[d*HW + p] - mn; s += expf(-10.f*t*t); }
  weight_fb[p] = (1.f - (s - 1.f)/31.f) * wmask_fb[p];
}

// cost volume: reduce over F (reads raw sad still stored in sfcv region)
__global__ void cv_kernel(const float* __restrict__ sadbase, const float* __restrict__ weight,
                          float* __restrict__ cvout) {
  int idx = blockIdx.x*blockDim.x + threadIdx.x;
  if (idx >= BB*DD*HW) return;
  int p = idx % HW;
  int d = (idx / HW) % DD;
  int b = idx / (DD*HW);
  float cv = 0.f, wsum = 0.f;
  for (int f = 0; f < FF; ++f) {
    float sd = sadbase[((f*BB+b)*DD + d)*HW + p];
    float wt = weight[(b*FF+f)*HW + p];
    cv += sd*wt; wsum += wt;
  }
  cvout[idx] = (wsum == 0.f) ? 0.f : 1.f - 2.f*cv/wsum;
}

// finalize sfcv in place: (1 - 2*sad) * wmask
__global__ void sfcv_kernel(float* __restrict__ base, const float* __restrict__ wmask) {
  int idx = blockIdx.x*blockDim.x + threadIdx.x;
  if (idx >= FF*BB*DD*HW) return;
  int p = idx % HW;
  int fb = idx / (DD*HW);        // f*BB + b
  int b = fb % BB, f = fb / BB;
  float v = base[idx];
  base[idx] = (1.f - 2.f*v) * wmask[(b*FF+f)*HW + p];
}

extern "C" void kernel_launch(void* const* d_in, const int* in_sizes, int n_in,
                              void* d_out, int out_size, void* d_ws, size_t ws_size,
                              hipStream_t stream) {
  const float* keyframe = (const float*)d_in[0];
  const float* frames   = (const float*)d_in[1];
  const float* kK       = (const float*)d_in[2];
  const float* Ks       = (const float*)d_in[3];
  const float* kpose    = (const float*)d_in[4];
  const float* poses    = (const float*)d_in[5];
  float* out = (float*)d_out;

  float* wsf    = (float*)d_ws;
  float* wsP    = wsf;                       // 48 floats (pad 64)
  float* wsIK   = wsf + 64;                  // 18 floats (pad to 256 total)
  float* wsWm   = wsf + 256;                 // B*F*HW   wmask, layout [b][f][hw]
  float* wsWt   = wsWm + BB*FF*HW;           // B*F*HW   weight, layout [b][f][hw]
  float* wsMuy  = wsWt + BB*FF*HW;           // B*C*HW
  float* wsSigy = wsMuy + BB*CC*HW;          // B*C*HW
  float* wsWimg = wsSigy + BB*CC*HW;         // D*C*HW   (reused per (b,f))
  float* wsDif  = wsWimg + DD*CC*HW;         // D*HW     (reused per (b,f))
  // total ~19.4M floats = 74 MB

  const int TPB = 256;
  setup_kernel<<<1, 64, 0, stream>>>(kK, Ks, kpose, poses, wsP, wsIK);
  kfstats_kernel<<<(BB*CC*HW + TPB-1)/TPB, TPB, 0, stream>>>(keyframe, wsMuy, wsSigy);
  for (int f = 0; f < FF; ++f)
    for (int b = 0; b < BB; ++b)
      mask_kernel<<<(HW + TPB-1)/TPB, TPB, 0, stream>>>(
          wsP + (f*BB+b)*12, wsIK + b*9, wsWm + (size_t)(b*FF+f)*HW);
  for (int f = 0; f < FF; ++f)
    for (int b = 0; b < BB; ++b) {
      const float* frame = frames + (size_t)(f*BB+b)*CC*HW;
      float* sadout = out + CV_SIZE + (size_t)(f*BB+b)*DD*HW;
      warp_kernel<<<(DD*HW + TPB-1)/TPB, TPB, 0, stream>>>(
          frame, wsP + (f*BB+b)*12, wsIK + b*9, wsWimg);
      ssim_kernel<<<(DD*HW + TPB-1)/TPB, TPB, 0, stream>>>(
          wsWimg, keyframe + (size_t)b*CC*HW, wsMuy + (size_t)b*CC*HW,
          wsSigy + (size_t)b*CC*HW, wsDif);
      sad_kernel<<<(DD*HW + TPB-1)/TPB, TPB, 0, stream>>>(wsDif, sadout);
    }
  for (int f = 0; f < FF; ++f)
    for (int b = 0; b < BB; ++b)
      weight_kernel<<<(HW + TPB-1)/TPB, TPB, 0, stream>>>(
          out + CV_SIZE + (size_t)(f*BB+b)*DD*HW,
          wsWm + (size_t)(b*FF+f)*HW, wsWt + (size_t)(b*FF+f)*HW);
  cv_kernel<<<(BB*DD*HW + TPB-1)/TPB, TPB, 0, stream>>>(out + CV_SIZE, wsWt, out);
  sfcv_kernel<<<(FF*BB*DD*HW + TPB-1)/TPB, TPB, 0, stream>>>(out + CV_SIZE, wsWm);
}

// Round 2
// 505.477 us; speedup vs baseline: 1.0831x; 1.0831x over previous
//
#include <hip/hip_runtime.h>

#define BB 2
#define FF 2
#define CC 3
#define HH 256
#define WW 512
#define DD 32
#define HW (HH*WW)
#define CV_SIZE (BB*DD*HW)

// tile geometry for fused warp+ssim+sad kernel
#define TH 8
#define TW 32
#define NTH (HH/TH)      // 32
#define NTW (WW/TW)      // 16
#define NT  (NTH*NTW)    // 512
#define RROWS (TH+4)     // 12  warp/kf tile rows (halo 2)
#define RCOLS (TW+4)     // 36
#define RSTR  (RCOLS+1)  // 37  (odd stride: no bank conflicts)
#define DROWS (TH+2)     // 10  diff tile rows (halo 1)
#define DCOLS (TW+2)     // 34
#define DSTR  (DCOLS+1)  // 35

__device__ __forceinline__ int refl(int i, int n) { return i < 0 ? -i : (i >= n ? 2*n-2-i : i); }

// 4x4 Gauss-Jordan inverse with partial pivoting (f32, matches jnp.linalg.inv)
__device__ void inv4(const float* m, float* out) {
  float a[4][8];
  for (int i = 0; i < 4; ++i)
    for (int j = 0; j < 4; ++j) { a[i][j] = m[i*4+j]; a[i][j+4] = (i==j) ? 1.f : 0.f; }
  for (int col = 0; col < 4; ++col) {
    int piv = col; float best = fabsf(a[col][col]);
    for (int r = col+1; r < 4; ++r) { float v = fabsf(a[r][col]); if (v > best) { best = v; piv = r; } }
    if (piv != col) for (int j = 0; j < 8; ++j) { float t = a[col][j]; a[col][j] = a[piv][j]; a[piv][j] = t; }
    float invd = 1.0f / a[col][col];
    for (int j = 0; j < 8; ++j) a[col][j] *= invd;
    for (int r = 0; r < 4; ++r) {
      if (r == col) continue;
      float f = a[r][col];
      for (int j = 0; j < 8; ++j) a[r][j] -= f * a[col][j];
    }
  }
  for (int i = 0; i < 4; ++i) for (int j = 0; j < 4; ++j) out[i*4+j] = a[i][j+4];
}

__global__ void setup_kernel(const float* __restrict__ kK, const float* __restrict__ Ks,
                             const float* __restrict__ kpose, const float* __restrict__ poses,
                             float* __restrict__ P, float* __restrict__ IK) {
  int t = threadIdx.x;
  if (t < BB) {
    float inv[16]; inv4(kK + t*16, inv);
    float* o = IK + t*9;
    o[0]=inv[0]; o[1]=inv[1]; o[2]=inv[2];
    o[3]=inv[4]; o[4]=inv[5]; o[5]=inv[6];
    o[6]=inv[8]; o[7]=inv[9]; o[8]=inv[10];
  }
  if (t >= 32 && t < 32 + FF*BB) {
    int i = t - 32;               // i = f*BB + b
    int b = i % BB;
    float ip[16]; inv4(poses + i*16, ip);
    float T[16];
    for (int r = 0; r < 4; ++r)
      for (int c = 0; c < 4; ++c) {
        float s = 0.f;
        for (int k = 0; k < 4; ++k) s += ip[r*4+k] * kpose[b*16 + k*4 + c];
        T[r*4+c] = s;
      }
    for (int r = 0; r < 3; ++r)
      for (int c = 0; c < 4; ++c) {
        float s = 0.f;
        for (int k = 0; k < 4; ++k) s += Ks[i*16 + r*4 + k] * T[k*4 + c];
        P[i*12 + r*4 + c] = s;
      }
  }
}

struct Proj { float x, y; };

__device__ __forceinline__ Proj project(const float* __restrict__ Pm,
                                        float camx, float camy, float camz, int d) {
  const float invd0 = 1.0f/3.0f;
  const float step  = (0.0125f - (1.0f/3.0f)) / 31.0f;
  float depth = 1.0f / (invd0 + step * (float)d);
  float X = depth*camx, Y = depth*camy, Z = depth*camz;
  float cp0 = Pm[0]*X + Pm[1]*Y + Pm[2]*Z  + Pm[3];
  float cp1 = Pm[4]*X + Pm[5]*Y + Pm[6]*Z  + Pm[7];
  float cp2 = Pm[8]*X + Pm[9]*Y + Pm[10]*Z + Pm[11];
  float den = cp2 + 1e-7f;
  float px = cp0 / den;
  float py = cp1 / den;
  float gx = px / (float)(WW-1);
  float gy = py / (float)(HH-1);
  gx = fminf(fmaxf((gx - 0.5f)*2.0f, -2.0f), 2.0f);
  gy = fminf(fmaxf((gy - 0.5f)*2.0f, -2.0f), 2.0f);
  Proj pr;
  pr.x = (gx + 1.0f) * ((float)WW*0.5f) - 0.5f;
  pr.y = (gy + 1.0f) * ((float)HH*0.5f) - 0.5f;
  return pr;
}

// Fused warp + SSIM + 3x3 box-sum. One block = one (fb, d, 8x32 tile).
// Writes raw sad directly into the sfcv region of d_out.
__global__ __launch_bounds__(256) void wss_kernel(
    const float* __restrict__ frames, const float* __restrict__ keyframe,
    const float* __restrict__ P, const float* __restrict__ IK,
    float* __restrict__ sadout) {
  __shared__ float lw[CC][RROWS][RSTR];   // warped+0.5 at reflected coords
  __shared__ float lk[CC][RROWS][RSTR];   // keyframe+0.5 at reflected coords
  __shared__ float ldf[DROWS][DSTR];      // channel-weighted ssim diff

  int bid = blockIdx.x;
  int tile = bid % NT;
  int d = (bid / NT) % DD;
  int fb = bid / (NT*DD);
  int b = fb % BB;
  int h0 = (tile / NTW) * TH;
  int w0 = (tile % NTW) * TW;
  const float* frame = frames + (size_t)fb*CC*HW;
  const float* kfb   = keyframe + (size_t)b*CC*HW;
  const float* Pm = P + fb*12;
  const float* ik = IK + b*9;
  int tid = threadIdx.x;

  // ---- phase 1: fill warp + kf LDS tiles at reflected coordinates ----
  for (int e = tid; e < RROWS*RCOLS; e += 256) {
    int i = e / RCOLS, j = e % RCOLS;
    int hr = refl(h0 - 2 + i, HH);
    int wr = refl(w0 - 2 + j, WW);
    float fw = (float)wr, fh = (float)hr;
    float camx = ik[0]*fw + ik[1]*fh + ik[2];
    float camy = ik[3]*fw + ik[4]*fh + ik[5];
    float camz = ik[6]*fw + ik[7]*fh + ik[8];
    Proj pr = project(Pm, camx, camy, camz, d);
    float x = pr.x, y = pr.y;
    float x0f = floorf(x), y0f = floorf(y);
    float x1f = x0f + 1.f, y1f = y0f + 1.f;
    float wa = (x1f-x)*(y1f-y);
    float wb = (x1f-x)*(y-y0f);
    float wc = (x-x0f)*(y1f-y);
    float wd = (x-x0f)*(y-y0f);
    bool vx0 = (x0f >= 0.f) && (x0f <= (float)(WW-1));
    bool vx1 = (x1f >= 0.f) && (x1f <= (float)(WW-1));
    bool vy0 = (y0f >= 0.f) && (y0f <= (float)(HH-1));
    bool vy1 = (y1f >= 0.f) && (y1f <= (float)(HH-1));
    int x0 = (int)fminf(fmaxf(x0f, 0.f), (float)(WW-1));
    int x1 = (int)fminf(fmaxf(x1f, 0.f), (float)(WW-1));
    int y0 = (int)fminf(fmaxf(y0f, 0.f), (float)(HH-1));
    int y1 = (int)fminf(fmaxf(y1f, 0.f), (float)(HH-1));
    #pragma unroll
    for (int c = 0; c < CC; ++c) {
      const float* im = frame + c*HW;
      float va = (vx0 && vy0) ? im[y0*WW + x0] : 0.f;
      float vb = (vx0 && vy1) ? im[y1*WW + x0] : 0.f;
      float vc = (vx1 && vy0) ? im[y0*WW + x1] : 0.f;
      float vd = (vx1 && vy1) ? im[y1*WW + x1] : 0.f;
      lw[c][i][j] = (va*wa + vb*wb + vc*wc + vd*wd) + 0.5f;
      lk[c][i][j] = kfb[c*HW + hr*WW + wr] + 0.5f;
    }
  }
  __syncthreads();

  // ---- phase 2: channel-weighted SSIM diff (halo 1 for box sum) ----
  for (int e = tid; e < DROWS*DCOLS; e += 256) {
    int i = e / DCOLS, j = e % DCOLS;
    int h = h0 - 1 + i, w = w0 - 1 + j;
    float val = 0.f;
    if (h >= 0 && h < HH && w >= 0 && w < WW) {
      const float cw[3] = {5.f/32.f, 16.f/32.f, 11.f/32.f};
      float acc = 0.f;
      #pragma unroll
      for (int c = 0; c < CC; ++c) {
        float sx=0.f, sxx=0.f, sxy=0.f, sy=0.f, syy=0.f;
        #pragma unroll
        for (int dy = 0; dy < 3; ++dy) {
          #pragma unroll
          for (int dx = 0; dx < 3; ++dx) {
            float xv = lw[c][i+dy][j+dx];
            float yv = lk[c][i+dy][j+dx];
            sx += xv; sxx += xv*xv; sxy += xv*yv; sy += yv; syy += yv*yv;
          }
        }
        float mux = sx / 9.0f;
        float muy = sy / 9.0f;
        float sigx = sxx/9.0f - mux*mux;
        float sigy = syy/9.0f - muy*muy;
        float sigxy = sxy/9.0f - mux*muy;
        float n  = (2.f*mux*muy + 1e-4f) * (2.f*sigxy + 9e-4f);
        float dn = (mux*mux + muy*muy + 1e-4f) * (sigx + sigy + 9e-4f);
        float v = (1.f - n/dn) * 0.5f;
        v = fminf(fmaxf(v, 0.f), 1.f);
        acc += cw[c]*v;
      }
      val = acc;
    }
    ldf[i][j] = val;
  }
  __syncthreads();

  // ---- phase 3: 3x3 zero-padded box sum / 9, write raw sad ----
  {
    int i = tid / TW, j = tid % TW;
    float s = 0.f;
    #pragma unroll
    for (int dy = 0; dy < 3; ++dy)
      #pragma unroll
      for (int dx = 0; dx < 3; ++dx)
        s += ldf[i+dy][j+dx];
    sadout[((size_t)fb*DD + d)*HW + (size_t)(h0+i)*WW + (w0+j)] = s / 9.0f;
  }
}

__device__ __forceinline__ float borderVal(float xif, float yif) {
  if (!((xif >= 0.f) && (xif <= (float)(WW-1)) && (yif >= 0.f) && (yif <= (float)(HH-1)))) return 0.f;
  int xi = (int)xif, yi = (int)yif;
  return (xi >= 2 && xi < WW-2 && yi >= 2 && yi < HH-2) ? 1.f : 0.f;
}

// Fused mask + weight + cost-volume + sfcv finalize. One thread = one (b, pixel).
__global__ __launch_bounds__(256) void final_kernel(
    const float* __restrict__ P, const float* __restrict__ IK,
    float* __restrict__ out) {
  int idx = blockIdx.x*blockDim.x + threadIdx.x;
  if (idx >= BB*HW) return;
  int p = idx % HW;
  int b = idx / HW;
  int w = p % WW, h = p / WW;
  float* sadbase = out + CV_SIZE;
  bool inb = (w >= 2 && w < WW-2 && h >= 2 && h < HH-2);

  float fw = (float)w, fh = (float)h;
  const float* ik = IK + b*9;
  float camx = ik[0]*fw + ik[1]*fh + ik[2];
  float camy = ik[3]*fw + ik[4]*fh + ik[5];
  float camz = ik[6]*fw + ik[7]*fh + ik[8];

  float cv[DD];
  #pragma unroll
  for (int d = 0; d < DD; ++d) cv[d] = 0.f;
  float wsum = 0.f;

  for (int f = 0; f < FF; ++f) {
    int fb = f*BB + b;
    const float* Pm = P + fb*12;
    // warp-validity mask (bilinear sample of border mask, AND over d)
    bool ok = true;
    for (int d = 0; d < DD; ++d) {
      Proj pr = project(Pm, camx, camy, camz, d);
      float x = pr.x, y = pr.y;
      float x0f = floorf(x), y0f = floorf(y);
      float x1f = x0f+1.f, y1f = y0f+1.f;
      float wa = (x1f-x)*(y1f-y);
      float wb = (x1f-x)*(y-y0f);
      float wc = (x-x0f)*(y1f-y);
      float wd = (x-x0f)*(y-y0f);
      float m = borderVal(x0f,y0f)*wa + borderVal(x0f,y1f)*wb +
                borderVal(x1f,y0f)*wc + borderVal(x1f,y1f)*wd;
      ok = ok && (m != 0.f);
    }
    float wmask = (inb && ok) ? 1.f : 0.f;

    float* sfb = sadbase + (size_t)fb*DD*HW + p;
    float sv[DD];
    float mn = 3.0e38f;
    #pragma unroll
    for (int d = 0; d < DD; ++d) { sv[d] = sfb[(size_t)d*HW]; mn = fminf(mn, sv[d]); }
    float s = 0.f;
    #pragma unroll
    for (int d = 0; d < DD; ++d) { float t = sv[d] - mn; s += expf(-10.f*t*t); }
    float wt = (1.f - (s - 1.f)/31.f) * wmask;
    wsum += wt;
    #pragma unroll
    for (int d = 0; d < DD; ++d) {
      cv[d] += sv[d]*wt;
      sfb[(size_t)d*HW] = (1.f - 2.f*sv[d]) * wmask;   // sfcv in place
    }
  }
  #pragma unroll
  for (int d = 0; d < DD; ++d)
    out[((size_t)b*DD + d)*HW + p] = (wsum == 0.f) ? 0.f : 1.f - 2.f*cv[d]/wsum;
}

extern "C" void kernel_launch(void* const* d_in, const int* in_sizes, int n_in,
                              void* d_out, int out_size, void* d_ws, size_t ws_size,
                              hipStream_t stream) {
  const float* keyframe = (const float*)d_in[0];
  const float* frames   = (const float*)d_in[1];
  const float* kK       = (const float*)d_in[2];
  const float* Ks       = (const float*)d_in[3];
  const float* kpose    = (const float*)d_in[4];
  const float* poses    = (const float*)d_in[5];
  float* out = (float*)d_out;

  float* wsP  = (float*)d_ws;        // 48 floats (pad 64)
  float* wsIK = (float*)d_ws + 64;   // 18 floats

  setup_kernel<<<1, 64, 0, stream>>>(kK, Ks, kpose, poses, wsP, wsIK);
  wss_kernel<<<FF*BB*DD*NT, 256, 0, stream>>>(frames, keyframe, wsP, wsIK, out + CV_SIZE);
  final_kernel<<<(BB*HW + 255)/256, 256, 0, stream>>>(wsP, wsIK, out);
}

// Round 3
// 300.389 us; speedup vs baseline: 1.8227x; 1.6827x over previous
//
#include <hip/hip_runtime.h>

#define BB 2
#define FF 2
#define CC 3
#define HH 256
#define WW 512
#define DD 32
#define HW (HH*WW)
#define CV_SIZE (BB*DD*HW)

#define SH 16                 // strip height (output rows per block)
#define NSTRIP (HH/SH)        // 16
#define NTHR 128              // threads per block; each owns 4 columns
#define INV9 (1.0f/9.0f)
#define C1f 1e-4f
#define C2f 9e-4f

__device__ __forceinline__ int refl(int i, int n) { return i < 0 ? -i : (i >= n ? 2*n-2-i : i); }

// 4x4 Gauss-Jordan inverse with partial pivoting (f32, matches jnp.linalg.inv)
__device__ void inv4(const float* m, float* out) {
  float a[4][8];
  for (int i = 0; i < 4; ++i)
    for (int j = 0; j < 4; ++j) { a[i][j] = m[i*4+j]; a[i][j+4] = (i==j) ? 1.f : 0.f; }
  for (int col = 0; col < 4; ++col) {
    int piv = col; float best = fabsf(a[col][col]);
    for (int r = col+1; r < 4; ++r) { float v = fabsf(a[r][col]); if (v > best) { best = v; piv = r; } }
    if (piv != col) for (int j = 0; j < 8; ++j) { float t = a[col][j]; a[col][j] = a[piv][j]; a[piv][j] = t; }
    float invd = 1.0f / a[col][col];
    for (int j = 0; j < 8; ++j) a[col][j] *= invd;
    for (int r = 0; r < 4; ++r) {
      if (r == col) continue;
      float f = a[r][col];
      for (int j = 0; j < 8; ++j) a[r][j] -= f * a[col][j];
    }
  }
  for (int i = 0; i < 4; ++i) for (int j = 0; j < 4; ++j) out[i*4+j] = a[i][j+4];
}

// Computes IK (3x3 inv intrinsics), P (3x4 proj), and M[fb][d] = depth*P[:,:3]*IK (+P[:,3] in col 2)
__global__ void setup_kernel(const float* __restrict__ kK, const float* __restrict__ Ks,
                             const float* __restrict__ kpose, const float* __restrict__ poses,
                             float* __restrict__ P, float* __restrict__ IK, float* __restrict__ M) {
  __shared__ float sIK[BB][9];
  __shared__ float sP[FF*BB][12];
  int t = threadIdx.x;
  if (t < BB) {
    float inv[16]; inv4(kK + t*16, inv);
    float* o = IK + t*9;
    float v0=inv[0], v1=inv[1], v2=inv[2], v3=inv[4], v4=inv[5], v5=inv[6], v6=inv[8], v7=inv[9], v8=inv[10];
    o[0]=v0;o[1]=v1;o[2]=v2;o[3]=v3;o[4]=v4;o[5]=v5;o[6]=v6;o[7]=v7;o[8]=v8;
    sIK[t][0]=v0;sIK[t][1]=v1;sIK[t][2]=v2;sIK[t][3]=v3;sIK[t][4]=v4;sIK[t][5]=v5;sIK[t][6]=v6;sIK[t][7]=v7;sIK[t][8]=v8;
  }
  if (t >= 32 && t < 32 + FF*BB) {
    int i = t - 32;               // i = f*BB + b
    int b = i % BB;
    float ip[16]; inv4(poses + i*16, ip);
    float T[16];
    for (int r = 0; r < 4; ++r)
      for (int c = 0; c < 4; ++c) {
        float s = 0.f;
        for (int k = 0; k < 4; ++k) s += ip[r*4+k] * kpose[b*16 + k*4 + c];
        T[r*4+c] = s;
      }
    for (int r = 0; r < 3; ++r)
      for (int c = 0; c < 4; ++c) {
        float s = 0.f;
        for (int k = 0; k < 4; ++k) s += Ks[i*16 + r*4 + k] * T[k*4 + c];
        P[i*12 + r*4 + c] = s;
        sP[i][r*4+c] = s;
      }
  }
  __syncthreads();
  if (t < FF*BB*DD) {             // 128 matrices
    int fb = t / DD, d = t % DD, b = fb % BB;
    const float invd0 = 1.0f/3.0f;
    const float step  = (0.0125f - (1.0f/3.0f)) / 31.0f;
    float depth = 1.0f / (invd0 + step * (float)d);
    for (int i = 0; i < 3; ++i)
      for (int j = 0; j < 3; ++j) {
        float s = sP[fb][i*4+0]*sIK[b][0*3+j] + sP[fb][i*4+1]*sIK[b][1*3+j] + sP[fb][i*4+2]*sIK[b][2*3+j];
        float mv = depth*s + ((j==2) ? sP[fb][i*4+3] : 0.f);
        M[t*12 + i*3 + j] = mv;
      }
  }
}

// keyframe SSIM stats (depth/frame independent): mu_y, sigma_y per (b,c,h,w)
__global__ void kfstats_kernel(const float* __restrict__ kf, float* __restrict__ muy,
                               float* __restrict__ sigy) {
  int idx = blockIdx.x*blockDim.x + threadIdx.x;
  if (idx >= BB*CC*HW) return;
  int w = idx % WW, h = (idx/WW) % HH;
  int bc = idx / HW;
  const float* ys = kf + bc*HW;
  float s = 0.f, s2 = 0.f;
  #pragma unroll
  for (int dy = -1; dy <= 1; ++dy) {
    int rh = refl(h+dy, HH);
    #pragma unroll
    for (int dx = -1; dx <= 1; ++dx) {
      int rw = refl(w+dx, WW);
      float yv = ys[rh*WW+rw] + 0.5f;
      s += yv; s2 += yv*yv;
    }
  }
  float mu = s / 9.0f;
  muy[idx] = mu;
  sigy[idx] = s2/9.0f - mu*mu;
}

// Samples warped row (slot) at image row hr (already reflected) for this thread's 4 columns.
#define SAMPLE(slot, hrarg) do { \
  int hr_ = (hrarg); \
  float fh_ = (float)hr_; \
  float b0_ = fmaf(m01, fh_, m02); \
  float b1_ = fmaf(m11, fh_, m12); \
  float b2_ = fmaf(m21, fh_, m22); \
  _Pragma("unroll") \
  for (int c_ = 0; c_ < CC; ++c_) { \
    const float4 yv_ = *(const float4*)(kfb + c_*HW + hr_*WW + w0); \
    yr[c_][slot][0] = yv_.x + 0.5f; yr[c_][slot][1] = yv_.y + 0.5f; \
    yr[c_][slot][2] = yv_.z + 0.5f; yr[c_][slot][3] = yv_.w + 0.5f; \
  } \
  _Pragma("unroll") \
  for (int k_ = 0; k_ < 4; ++k_) { \
    float fw_ = (float)(w0 + k_); \
    float cp0_ = fmaf(m00, fw_, b0_); \
    float cp1_ = fmaf(m10, fw_, b1_); \
    float cp2_ = fmaf(m20, fw_, b2_); \
    float den_ = cp2_ + 1e-7f; \
    float rd_ = __builtin_amdgcn_rcpf(den_); \
    float px_ = cp0_*rd_, py_ = cp1_*rd_; \
    float gx_ = fminf(fmaxf((px_*(1.0f/511.0f) - 0.5f)*2.0f, -2.0f), 2.0f); \
    float gy_ = fminf(fmaxf((py_*(1.0f/255.0f) - 0.5f)*2.0f, -2.0f), 2.0f); \
    float x_ = (gx_ + 1.0f)*((float)WW*0.5f) - 0.5f; \
    float y_ = (gy_ + 1.0f)*((float)HH*0.5f) - 0.5f; \
    float x0f_ = floorf(x_), y0f_ = floorf(y_); \
    float x1f_ = x0f_ + 1.f, y1f_ = y0f_ + 1.f; \
    float wa_ = (x1f_-x_)*(y1f_-y_); \
    float wb_ = (x1f_-x_)*(y_-y0f_); \
    float wc_ = (x_-x0f_)*(y1f_-y_); \
    float wd_ = (x_-x0f_)*(y_-y0f_); \
    bool vx0_ = (x0f_ >= 0.f) && (x0f_ <= (float)(WW-1)); \
    bool vx1_ = (x1f_ >= 0.f) && (x1f_ <= (float)(WW-1)); \
    bool vy0_ = (y0f_ >= 0.f) && (y0f_ <= (float)(HH-1)); \
    bool vy1_ = (y1f_ >= 0.f) && (y1f_ <= (float)(HH-1)); \
    int xi0_ = (int)fminf(fmaxf(x0f_, 0.f), (float)(WW-1)); \
    int xi1_ = (int)fminf(fmaxf(x1f_, 0.f), (float)(WW-1)); \
    int yi0_ = (int)fminf(fmaxf(y0f_, 0.f), (float)(HH-1)); \
    int yi1_ = (int)fminf(fmaxf(y1f_, 0.f), (float)(HH-1)); \
    int i00_ = yi0_*WW + xi0_, i01_ = yi1_*WW + xi0_; \
    int i10_ = yi0_*WW + xi1_, i11_ = yi1_*WW + xi1_; \
    _Pragma("unroll") \
    for (int c_ = 0; c_ < CC; ++c_) { \
      const float* im_ = frame + c_*HW; \
      float va_ = (vx0_ && vy0_) ? im_[i00_] : 0.f; \
      float vb2_ = (vx0_ && vy1_) ? im_[i01_] : 0.f; \
      float vc2_ = (vx1_ && vy0_) ? im_[i10_] : 0.f; \
      float vd2_ = (vx1_ && vy1_) ? im_[i11_] : 0.f; \
      xr[c_][slot][k_] = fmaf(va_, wa_, fmaf(vb2_, wb_, fmaf(vc2_, wc_, vd2_*wd_))) + 0.5f; \
    } \
  } \
} while (0)

// Horizontal 3-sum with LDS edge exchange; reflect handled by register substitute at image edges.
#define HSUM(arr, v, o) do { \
  float L_ = sb[pb][arr][1][tm]; \
  float R_ = sb[pb][arr][0][tp]; \
  if (t == 0) L_ = (v)[1]; \
  if (t == NTHR-1) R_ = (v)[2]; \
  float p01_ = (v)[0] + (v)[1]; \
  float p12_ = (v)[1] + (v)[2]; \
  float p23_ = (v)[2] + (v)[3]; \
  (o)[0] = L_ + p01_; (o)[1] = p01_ + (v)[2]; \
  (o)[2] = p12_ + (v)[3]; (o)[3] = p23_ + R_; \
} while (0)

// Fused warp + SSIM + box-sum, register-rolling over rows, one (fb,d,strip) per block.
__global__ __launch_bounds__(NTHR) void wss2_kernel(
    const float* __restrict__ frames, const float* __restrict__ keyframe,
    const float* __restrict__ M, const float* __restrict__ muy, const float* __restrict__ sigy,
    float* __restrict__ sadout) {
  __shared__ float sb[2][10][2][NTHR];   // [parity][array: 9 vs + 1 vb][L/R edge][thread]

  int bid = blockIdx.x;
  int strip = bid & (NSTRIP-1);
  int d  = (bid >> 4) & (DD-1);
  int fb = bid >> 9;
  int b = fb % BB;
  int h0 = strip * SH;
  int t = threadIdx.x;
  int w0 = t*4;
  int tm = (t > 0) ? t-1 : 0;
  int tp = (t < NTHR-1) ? t+1 : NTHR-1;

  const float* Mp = M + (fb*DD + d)*12;
  float m00=Mp[0], m01=Mp[1], m02=Mp[2];
  float m10=Mp[3], m11=Mp[4], m12=Mp[5];
  float m20=Mp[6], m21=Mp[7], m22=Mp[8];
  const float* frame = frames + (size_t)fb*CC*HW;
  const float* kfb   = keyframe + (size_t)b*CC*HW;
  const float* muyb  = muy + (size_t)b*CC*HW;
  const float* sigyb = sigy + (size_t)b*CC*HW;
  float* sadp = sadout + (size_t)(fb*DD + d)*HW;

  float xr[CC][3][4], yr[CC][3][4], df[3][4];
  #pragma unroll
  for (int k = 0; k < 4; ++k) { df[0][k]=0.f; df[1][k]=0.f; df[2][k]=0.f; }

  SAMPLE(0, refl(h0-2, HH));
  SAMPLE(1, refl(h0-1, HH));

  for (int r = h0-1; r <= h0+SH+1; ++r) {
    int pb = r & 1;
    // ---- phase 1: sample next row; vertical sums; LDS edge writes ----
    SAMPLE(2, refl(r+1, HH));
    float vs[CC][3][4];
    #pragma unroll
    for (int c = 0; c < CC; ++c) {
      #pragma unroll
      for (int k = 0; k < 4; ++k) {
        float x0 = xr[c][0][k], x1 = xr[c][1][k], x2 = xr[c][2][k];
        float y0 = yr[c][0][k], y1 = yr[c][1][k], y2 = yr[c][2][k];
        vs[c][0][k] = (x0 + x1) + x2;
        vs[c][1][k] = fmaf(x2, x2, fmaf(x1, x1, x0*x0));
        vs[c][2][k] = fmaf(x2, y2, fmaf(x1, y1, x0*y0));
      }
      sb[pb][c*3+0][0][t] = vs[c][0][0]; sb[pb][c*3+0][1][t] = vs[c][0][3];
      sb[pb][c*3+1][0][t] = vs[c][1][0]; sb[pb][c*3+1][1][t] = vs[c][1][3];
      sb[pb][c*3+2][0][t] = vs[c][2][0]; sb[pb][c*3+2][1][t] = vs[c][2][3];
    }
    float vb[4];
    #pragma unroll
    for (int k = 0; k < 4; ++k) vb[k] = (df[0][k] + df[1][k]) + df[2][k];
    sb[pb][9][0][t] = vb[0]; sb[pb][9][1][t] = vb[3];
    __syncthreads();

    // ---- phase 2: horizontal sums, SSIM epilogue -> diff row r; sad row r-2 ----
    #pragma unroll
    for (int k = 0; k < 4; ++k) { df[0][k] = df[1][k]; df[1][k] = df[2][k]; }
    bool rowvalid = (r >= 0) && (r < HH);
    float nd[4] = {0.f, 0.f, 0.f, 0.f};
    if (rowvalid) {
      float accv[4] = {0.f, 0.f, 0.f, 0.f};
      #pragma unroll
      for (int c = 0; c < CC; ++c) {
        float hx[4], hxx[4], hxy[4];
        HSUM(c*3+0, vs[c][0], hx);
        HSUM(c*3+1, vs[c][1], hxx);
        HSUM(c*3+2, vs[c][2], hxy);
        const float4 mu4 = *(const float4*)(muyb + c*HW + r*WW + w0);
        const float4 sg4 = *(const float4*)(sigyb + c*HW + r*WW + w0);
        float muv[4] = {mu4.x, mu4.y, mu4.z, mu4.w};
        float sgv[4] = {sg4.x, sg4.y, sg4.z, sg4.w};
        float cwc = (c==0) ? (5.f/32.f) : ((c==1) ? (16.f/32.f) : (11.f/32.f));
        #pragma unroll
        for (int k = 0; k < 4; ++k) {
          float mux = hx[k]*INV9;
          float sigx = fmaf(-mux, mux, hxx[k]*INV9);
          float sigxy = fmaf(-mux, muv[k], hxy[k]*INV9);
          float nn  = (2.f*mux*muv[k] + C1f) * (2.f*sigxy + C2f);
          float ddn = fmaf(mux, mux, fmaf(muv[k], muv[k], C1f)) * ((sigx + sgv[k]) + C2f);
          float v = (1.f - nn*__builtin_amdgcn_rcpf(ddn))*0.5f;
          v = fminf(fmaxf(v, 0.f), 1.f);
          accv[k] = fmaf(cwc, v, accv[k]);
        }
      }
      nd[0]=accv[0]; nd[1]=accv[1]; nd[2]=accv[2]; nd[3]=accv[3];
    }
    df[2][0]=nd[0]; df[2][1]=nd[1]; df[2][2]=nd[2]; df[2][3]=nd[3];

    int s = r - 2;
    if (s >= h0 && s < h0 + SH) {
      float Lb = (t == 0)      ? 0.f : sb[pb][9][1][tm];
      float Rb = (t == NTHR-1) ? 0.f : sb[pb][9][0][tp];
      float p01 = vb[0]+vb[1], p12 = vb[1]+vb[2], p23 = vb[2]+vb[3];
      float4 o;
      o.x = (Lb + p01)*INV9;
      o.y = (p01 + vb[2])*INV9;
      o.z = (p12 + vb[3])*INV9;
      o.w = (p23 + Rb)*INV9;
      *(float4*)(sadp + (size_t)s*WW + w0) = o;
    }
    // shift input row windows
    #pragma unroll
    for (int c = 0; c < CC; ++c)
      #pragma unroll
      for (int k = 0; k < 4; ++k) {
        xr[c][0][k]=xr[c][1][k]; xr[c][1][k]=xr[c][2][k];
        yr[c][0][k]=yr[c][1][k]; yr[c][1][k]=yr[c][2][k];
      }
  }
}

struct Proj { float x, y; };

__device__ __forceinline__ Proj project(const float* __restrict__ Pm,
                                        float camx, float camy, float camz, int d) {
  const float invd0 = 1.0f/3.0f;
  const float step  = (0.0125f - (1.0f/3.0f)) / 31.0f;
  float depth = 1.0f / (invd0 + step * (float)d);
  float X = depth*camx, Y = depth*camy, Z = depth*camz;
  float cp0 = Pm[0]*X + Pm[1]*Y + Pm[2]*Z  + Pm[3];
  float cp1 = Pm[4]*X + Pm[5]*Y + Pm[6]*Z  + Pm[7];
  float cp2 = Pm[8]*X + Pm[9]*Y + Pm[10]*Z + Pm[11];
  float den = cp2 + 1e-7f;
  float px = cp0 / den;
  float py = cp1 / den;
  float gx = px / (float)(WW-1);
  float gy = py / (float)(HH-1);
  gx = fminf(fmaxf((gx - 0.5f)*2.0f, -2.0f), 2.0f);
  gy = fminf(fmaxf((gy - 0.5f)*2.0f, -2.0f), 2.0f);
  Proj pr;
  pr.x = (gx + 1.0f) * ((float)WW*0.5f) - 0.5f;
  pr.y = (gy + 1.0f) * ((float)HH*0.5f) - 0.5f;
  return pr;
}

__device__ __forceinline__ float borderVal(float xif, float yif) {
  if (!((xif >= 0.f) && (xif <= (float)(WW-1)) && (yif >= 0.f) && (yif <= (float)(HH-1)))) return 0.f;
  int xi = (int)xif, yi = (int)yif;
  return (xi >= 2 && xi < WW-2 && yi >= 2 && yi < HH-2) ? 1.f : 0.f;
}

// Fused mask + weight + cost-volume + sfcv finalize. One thread = one (b, pixel).
__global__ __launch_bounds__(256) void final_kernel(
    const float* __restrict__ P, const float* __restrict__ IK,
    float* __restrict__ out) {
  int idx = blockIdx.x*blockDim.x + threadIdx.x;
  if (idx >= BB*HW) return;
  int p = idx % HW;
  int b = idx / HW;
  int w = p % WW, h = p / WW;
  float* sadbase = out + CV_SIZE;
  bool inb = (w >= 2 && w < WW-2 && h >= 2 && h < HH-2);

  float fw = (float)w, fh = (float)h;
  const float* ik = IK + b*9;
  float camx = ik[0]*fw + ik[1]*fh + ik[2];
  float camy = ik[3]*fw + ik[4]*fh + ik[5];
  float camz = ik[6]*fw + ik[7]*fh + ik[8];

  float cv[DD];
  #pragma unroll
  for (int d = 0; d < DD; ++d) cv[d] = 0.f;
  float wsum = 0.f;

  for (int f = 0; f < FF; ++f) {
    int fb = f*BB + b;
    const float* Pm = P + fb*12;
    bool ok = true;
    for (int d = 0; d < DD; ++d) {
      Proj pr = project(Pm, camx, camy, camz, d);
      float x = pr.x, y = pr.y;
      float x0f = floorf(x), y0f = floorf(y);
      float x1f = x0f+1.f, y1f = y0f+1.f;
      float wa = (x1f-x)*(y1f-y);
      float wb = (x1f-x)*(y-y0f);
      float wc = (x-x0f)*(y1f-y);
      float wd = (x-x0f)*(y-y0f);
      float m = borderVal(x0f,y0f)*wa + borderVal(x0f,y1f)*wb +
                borderVal(x1f,y0f)*wc + borderVal(x1f,y1f)*wd;
      ok = ok && (m != 0.f);
    }
    float wmask = (inb && ok) ? 1.f : 0.f;

    float* sfb = sadbase + (size_t)fb*DD*HW + p;
    float sv[DD];
    float mn = 3.0e38f;
    #pragma unroll
    for (int d = 0; d < DD; ++d) { sv[d] = sfb[(size_t)d*HW]; mn = fminf(mn, sv[d]); }
    float s = 0.f;
    #pragma unroll
    for (int d = 0; d < DD; ++d) { float tt = sv[d] - mn; s += expf(-10.f*tt*tt); }
    float wt = (1.f - (s - 1.f)/31.f) * wmask;
    wsum += wt;
    #pragma unroll
    for (int d = 0; d < DD; ++d) {
      cv[d] += sv[d]*wt;
      sfb[(size_t)d*HW] = (1.f - 2.f*sv[d]) * wmask;   // sfcv in place
    }
  }
  #pragma unroll
  for (int d = 0; d < DD; ++d)
    out[((size_t)b*DD + d)*HW + p] = (wsum == 0.f) ? 0.f : 1.f - 2.f*cv[d]/wsum;
}

extern "C" void kernel_launch(void* const* d_in, const int* in_sizes, int n_in,
                              void* d_out, int out_size, void* d_ws, size_t ws_size,
                              hipStream_t stream) {
  const float* keyframe = (const float*)d_in[0];
  const float* frames   = (const float*)d_in[1];
  const float* kK       = (const float*)d_in[2];
  const float* Ks       = (const float*)d_in[3];
  const float* kpose    = (const float*)d_in[4];
  const float* poses    = (const float*)d_in[5];
  float* out = (float*)d_out;

  float* wsP   = (float*)d_ws;            // 48 floats (pad 64)
  float* wsIK  = wsP + 64;                // 18 floats (pad 64)
  float* wsM   = wsIK + 64;               // 128*12 floats (pad to 2048 total below)
  float* wsMuy = (float*)d_ws + 2048;     // B*C*HW
  float* wsSigy= wsMuy + BB*CC*HW;        // B*C*HW

  setup_kernel<<<1, 128, 0, stream>>>(kK, Ks, kpose, poses, wsP, wsIK, wsM);
  kfstats_kernel<<<(BB*CC*HW + 255)/256, 256, 0, stream>>>(keyframe, wsMuy, wsSigy);
  wss2_kernel<<<FF*BB*DD*NSTRIP, NTHR, 0, stream>>>(frames, keyframe, wsM, wsMuy, wsSigy, out + CV_SIZE);
  final_kernel<<<(BB*HW + 255)/256, 256, 0, stream>>>(wsP, wsIK, out);
}